// Round 12
// baseline (123.246 us; speedup 1.0000x reference)
//
#include <hip/hip_runtime.h>

typedef __attribute__((ext_vector_type(4))) _Float16 f16x4;
typedef __attribute__((ext_vector_type(8))) _Float16 f16x8;
typedef __attribute__((ext_vector_type(4))) float f32x4;

#define NWIN 49
#define NH 8
#define CCH 256

__device__ __forceinline__ uint cvt2_u32(float a, float b) {
    auto t = __builtin_amdgcn_cvt_pkrtz(a, b);
    return *(uint*)&t;
}
__device__ __forceinline__ f16x4 mk4(uint a, uint b) {
    union { uint u[2]; f16x4 v; } x;
    x.u[0] = a; x.u[1] = b;
    return x.v;
}
__device__ __forceinline__ f16x8 mk8(uint a, uint b, uint c, uint d) {
    union { uint u[4]; f16x8 v; } x;
    x.u[0] = a; x.u[1] = b; x.u[2] = c; x.u[3] = d;
    return x.v;
}
__device__ __forceinline__ float bias_elem(uint2 bb, int r) {
    union { uint u; _Float16 h[2]; } x;
    x.u = (r < 2) ? bb.x : bb.y;
    return (float)x.h[r & 1];
}

// --- Prologue (fused): bias table in fp16-packed S^T fragment layout.
// tile tix=((h*4+jt)*4+it); lane stores uint2 (4 fp16) = log2e*bias for r=0..3;
// j>=49 -> -inf (exp2->0), i>=49 -> 0. MLP 2->64->8 computed inline per lane.
__global__ void bias16_kernel(const float* __restrict__ W1, const float* __restrict__ b1,
                              const float* __restrict__ W2, const float* __restrict__ b2,
                              uint* __restrict__ bfrag16) {
    int blk = blockIdx.x;           // ((h*4 + jt)*4 + it), 128 blocks
    int it = blk & 3, jt = (blk >> 2) & 3, h = blk >> 4;
    int lane = threadIdx.x;
    int g = lane >> 4, l15 = lane & 15;
    int i = it * 16 + l15;
    int ic = i < NWIN ? i : NWIN - 1;
    float dh[4], dw[4], outv[4];
#pragma unroll
    for (int r = 0; r < 4; ++r) {
        int j = jt * 16 + g * 4 + r;
        int jc = j < NWIN ? j : NWIN - 1;
        dh[r] = (float)(ic / 7 - jc / 7);
        dw[r] = (float)(ic % 7 - jc % 7);
        outv[r] = b2[h];
    }
    for (int u = 0; u < 64; ++u) {
        float w1a = W1[u], w1b = W1[64 + u], bu = b1[u], w2 = W2[u * NH + h];
#pragma unroll
        for (int r = 0; r < 4; ++r) {
            float hv = fmaxf(fmaf(dh[r], w1a, fmaf(dw[r], w1b, bu)), 0.0f);
            outv[r] = fmaf(hv, w2, outv[r]);
        }
    }
    _Float16 hv16[4];
#pragma unroll
    for (int r = 0; r < 4; ++r) {
        int j = jt * 16 + g * 4 + r;
        float val;
        if (j >= NWIN) val = -__builtin_inff();
        else if (i >= NWIN) val = 0.0f;
        else val = outv[r] * 1.4426950408889634f;
        hv16[r] = (_Float16)val;
    }
    union { _Float16 h[4]; uint2 u; } pk;
    pk.h[0] = hv16[0]; pk.h[1] = hv16[1]; pk.h[2] = hv16[2]; pk.h[3] = hv16[3];
    *(uint2*)(bfrag16 + (size_t)blk * 128 + lane * 2) = pk.u;
}

// --- Main: 512 threads = 8 waves = 8 heads of a window PAIR; each wave does
// TWO independent (window, head) problems (windows 2b, 2b+1, same head ->
// shared fp16 bias regs). Zero LDS; in-register P via 16x16x16 PV.
__global__ __launch_bounds__(512, 2) void attn_kernel(
    const float* __restrict__ q, const float* __restrict__ k,
    const float* __restrict__ v, const uint* __restrict__ bfrag16,
    float* __restrict__ out) {
    // Bijective XCD swizzle (gridDim.x = 1024, divisible by 8)
    const int nper = (int)(gridDim.x >> 3);
    const int bw = ((int)blockIdx.x & 7) * nper + ((int)blockIdx.x >> 3);

    const int tid = threadIdx.x;
    const int w = tid >> 6, lane = tid & 63;   // w = head
    const int h = w;
    const int g = lane >> 4, l15 = lane & 15;
    const size_t baseA = (size_t)(2 * bw) * (NWIN * CCH) + h * 32;
    const size_t baseB = baseA + (size_t)NWIN * CCH;

    // ======== Phase 0: issue A.kq, A.v, B.kq, bias (B.v issued later) ========
    float4 kA[4][2], qA[4][2], kB[4][2], qB[4][2];
#pragma unroll
    for (int t = 0; t < 4; ++t) {
        int row = t * 16 + l15;
        int rc = row < NWIN ? row : NWIN - 1;
        const float* kpA = k + baseA + (size_t)rc * CCH + g * 8;
        const float* qpA = q + baseA + (size_t)rc * CCH + g * 8;
        const float* kpB = k + baseB + (size_t)rc * CCH + g * 8;
        const float* qpB = q + baseB + (size_t)rc * CCH + g * 8;
        kA[t][0] = *(const float4*)kpA; kA[t][1] = *(const float4*)(kpA + 4);
        qA[t][0] = *(const float4*)qpA; qA[t][1] = *(const float4*)(qpA + 4);
        kB[t][0] = *(const float4*)kpB; kB[t][1] = *(const float4*)(kpB + 4);
        qB[t][0] = *(const float4*)qpB; qB[t][1] = *(const float4*)(qpB + 4);
    }
    float vA[4][2][4];   // [jt][nt][r] = V[jt*16+4g+r][nt*16+l15]
#pragma unroll
    for (int jt = 0; jt < 4; ++jt)
#pragma unroll
        for (int nt = 0; nt < 2; ++nt)
#pragma unroll
            for (int r = 0; r < 4; ++r) {
                int j = jt * 16 + 4 * g + r;
                int jc = j < NWIN ? j : NWIN - 1;
                vA[jt][nt][r] = v[baseA + (size_t)jc * CCH + nt * 16 + l15];
            }
    uint2 bb16[4][4];    // shared by A and B (same head)
#pragma unroll
    for (int jt = 0; jt < 4; ++jt)
#pragma unroll
        for (int it = 0; it < 4; ++it)
            bb16[jt][it] = *(const uint2*)(bfrag16 + (size_t)((h * 4 + jt) * 4 + it) * 128 + lane * 2);

    const float scale2 = 0.17677669529663687f * 1.4426950408889634f;

    // ======== Window A ========
#pragma unroll
    for (int t = 0; t < 4; ++t)
        asm volatile("" :: "v"(kA[t][0].x), "v"(kA[t][1].x), "v"(qA[t][0].x), "v"(qA[t][1].x));
    f16x8 ka16[4], qb16[4];
#pragma unroll
    for (int t = 0; t < 4; ++t) {
        float4 a = kA[t][0], c = kA[t][1], d = qA[t][0], e = qA[t][1];
        ka16[t] = mk8(cvt2_u32(a.x, a.y), cvt2_u32(a.z, a.w), cvt2_u32(c.x, c.y), cvt2_u32(c.z, c.w));
        qb16[t] = mk8(cvt2_u32(d.x, d.y), cvt2_u32(d.z, d.w), cvt2_u32(e.x, e.y), cvt2_u32(e.z, e.w));
    }
    f32x4 acc[4][4];
#pragma unroll
    for (int jt = 0; jt < 4; ++jt)
#pragma unroll
        for (int it = 0; it < 4; ++it) {
            f32x4 a = {0.f, 0.f, 0.f, 0.f};
            acc[jt][it] = __builtin_amdgcn_mfma_f32_16x16x32_f16(ka16[jt], qb16[it], a, 0, 0, 0);
        }
#pragma unroll
    for (int jt = 0; jt < 4; ++jt)
        asm volatile("" :: "v"(bb16[jt][0].x), "v"(bb16[jt][1].x), "v"(bb16[jt][2].x), "v"(bb16[jt][3].x));

    f16x4 pf[4][4];
#pragma unroll
    for (int it = 0; it < 4; ++it) {
        float p[16];
        float s = 0.0f;
#pragma unroll
        for (int jt = 0; jt < 4; ++jt)
#pragma unroll
            for (int r = 0; r < 4; ++r) {
                float e = __builtin_amdgcn_exp2f(fmaf(acc[jt][it][r], scale2, bias_elem(bb16[jt][it], r)));
                p[jt * 4 + r] = e;
                s += e;
            }
        s += __shfl_xor(s, 16);
        s += __shfl_xor(s, 32);
        const float inv = 1.0f / s;
#pragma unroll
        for (int jt = 0; jt < 4; ++jt)
            pf[jt][it] = mk4(cvt2_u32(p[jt * 4 + 0] * inv, p[jt * 4 + 1] * inv),
                             cvt2_u32(p[jt * 4 + 2] * inv, p[jt * 4 + 3] * inv));
    }
#pragma unroll
    for (int jt = 0; jt < 4; ++jt)
        asm volatile("" :: "v"(vA[jt][0][0]), "v"(vA[jt][0][3]), "v"(vA[jt][1][0]), "v"(vA[jt][1][3]));
    f16x4 vf[4][2];
#pragma unroll
    for (int jt = 0; jt < 4; ++jt)
#pragma unroll
        for (int nt = 0; nt < 2; ++nt)
            vf[jt][nt] = mk4(cvt2_u32(vA[jt][nt][0], vA[jt][nt][1]), cvt2_u32(vA[jt][nt][2], vA[jt][nt][3]));
    f32x4 oacc[4][2];
#pragma unroll
    for (int mt = 0; mt < 4; ++mt)
#pragma unroll
        for (int nt = 0; nt < 2; ++nt) oacc[mt][nt] = (f32x4){0.f, 0.f, 0.f, 0.f};
#pragma unroll
    for (int jt = 0; jt < 4; ++jt)
#pragma unroll
        for (int mt = 0; mt < 4; ++mt)
#pragma unroll
            for (int nt = 0; nt < 2; ++nt)
                oacc[mt][nt] = __builtin_amdgcn_mfma_f32_16x16x16f16(pf[jt][mt], vf[jt][nt], oacc[mt][nt], 0, 0, 0);
#pragma unroll
    for (int mt = 0; mt < 4; ++mt)
#pragma unroll
        for (int r = 0; r < 4; ++r) {
            int i = mt * 16 + g * 4 + r;
            if (i < NWIN) {
                float* op = out + baseA + (size_t)i * CCH + l15;
                op[0]  = oacc[mt][0][r];
                op[16] = oacc[mt][1][r];
            }
        }

    // ======== issue B.v now (hides under B's QK + softmax) ========
    float vB[4][2][4];
#pragma unroll
    for (int jt = 0; jt < 4; ++jt)
#pragma unroll
        for (int nt = 0; nt < 2; ++nt)
#pragma unroll
            for (int r = 0; r < 4; ++r) {
                int j = jt * 16 + 4 * g + r;
                int jc = j < NWIN ? j : NWIN - 1;
                vB[jt][nt][r] = v[baseB + (size_t)jc * CCH + nt * 16 + l15];
            }

    // ======== Window B (loads landed long ago; bias regs reused) ========
#pragma unroll
    for (int t = 0; t < 4; ++t)
        asm volatile("" :: "v"(kB[t][0].x), "v"(kB[t][1].x), "v"(qB[t][0].x), "v"(qB[t][1].x));
#pragma unroll
    for (int t = 0; t < 4; ++t) {
        float4 a = kB[t][0], c = kB[t][1], d = qB[t][0], e = qB[t][1];
        ka16[t] = mk8(cvt2_u32(a.x, a.y), cvt2_u32(a.z, a.w), cvt2_u32(c.x, c.y), cvt2_u32(c.z, c.w));
        qb16[t] = mk8(cvt2_u32(d.x, d.y), cvt2_u32(d.z, d.w), cvt2_u32(e.x, e.y), cvt2_u32(e.z, e.w));
    }
#pragma unroll
    for (int jt = 0; jt < 4; ++jt)
#pragma unroll
        for (int it = 0; it < 4; ++it) {
            f32x4 a = {0.f, 0.f, 0.f, 0.f};
            acc[jt][it] = __builtin_amdgcn_mfma_f32_16x16x32_f16(ka16[jt], qb16[it], a, 0, 0, 0);
        }
#pragma unroll
    for (int it = 0; it < 4; ++it) {
        float p[16];
        float s = 0.0f;
#pragma unroll
        for (int jt = 0; jt < 4; ++jt)
#pragma unroll
            for (int r = 0; r < 4; ++r) {
                float e = __builtin_amdgcn_exp2f(fmaf(acc[jt][it][r], scale2, bias_elem(bb16[jt][it], r)));
                p[jt * 4 + r] = e;
                s += e;
            }
        s += __shfl_xor(s, 16);
        s += __shfl_xor(s, 32);
        const float inv = 1.0f / s;
#pragma unroll
        for (int jt = 0; jt < 4; ++jt)
            pf[jt][it] = mk4(cvt2_u32(p[jt * 4 + 0] * inv, p[jt * 4 + 1] * inv),
                             cvt2_u32(p[jt * 4 + 2] * inv, p[jt * 4 + 3] * inv));
    }
#pragma unroll
    for (int jt = 0; jt < 4; ++jt)
        asm volatile("" :: "v"(vB[jt][0][0]), "v"(vB[jt][0][3]), "v"(vB[jt][1][0]), "v"(vB[jt][1][3]));
#pragma unroll
    for (int jt = 0; jt < 4; ++jt)
#pragma unroll
        for (int nt = 0; nt < 2; ++nt)
            vf[jt][nt] = mk4(cvt2_u32(vB[jt][nt][0], vB[jt][nt][1]), cvt2_u32(vB[jt][nt][2], vB[jt][nt][3]));
#pragma unroll
    for (int mt = 0; mt < 4; ++mt)
#pragma unroll
        for (int nt = 0; nt < 2; ++nt) oacc[mt][nt] = (f32x4){0.f, 0.f, 0.f, 0.f};
#pragma unroll
    for (int jt = 0; jt < 4; ++jt)
#pragma unroll
        for (int mt = 0; mt < 4; ++mt)
#pragma unroll
            for (int nt = 0; nt < 2; ++nt)
                oacc[mt][nt] = __builtin_amdgcn_mfma_f32_16x16x16f16(pf[jt][mt], vf[jt][nt], oacc[mt][nt], 0, 0, 0);
#pragma unroll
    for (int mt = 0; mt < 4; ++mt)
#pragma unroll
        for (int r = 0; r < 4; ++r) {
            int i = mt * 16 + g * 4 + r;
            if (i < NWIN) {
                float* op = out + baseB + (size_t)i * CCH + l15;
                op[0]  = oacc[mt][0][r];
                op[16] = oacc[mt][1][r];
            }
        }
}

extern "C" void kernel_launch(void* const* d_in, const int* in_sizes, int n_in,
                              void* d_out, int out_size, void* d_ws, size_t ws_size,
                              hipStream_t stream) {
    const float* q  = (const float*)d_in[0];
    const float* k  = (const float*)d_in[1];
    const float* v  = (const float*)d_in[2];
    const float* W1 = (const float*)d_in[3];
    const float* b1 = (const float*)d_in[4];
    const float* W2 = (const float*)d_in[5];
    const float* b2 = (const float*)d_in[6];

    uint* bfrag16 = (uint*)d_ws;                       // 128*128 uint = 64 KB
    float* out    = (float*)d_out;

    const int B = in_sizes[0] / (NWIN * CCH);          // 2048

    bias16_kernel<<<128, 64, 0, stream>>>(W1, b1, W2, b2, bfrag16);
    attn_kernel<<<B / 2, 512, 0, stream>>>(q, k, v, bfrag16, out);
}

// Round 14
// 111.517 us; speedup vs baseline: 1.1052x; 1.1052x over previous
//
#include <hip/hip_runtime.h>

typedef __attribute__((ext_vector_type(4))) _Float16 f16x4;
typedef __attribute__((ext_vector_type(8))) _Float16 f16x8;
typedef __attribute__((ext_vector_type(4))) float f32x4;

#define NWIN 49
#define NH 8
#define CCH 256
#define NF4 3136      // 49*256/4 float4s per tensor-window
#define QROW 264      // fp16 row stride for qh/kh (16B-aligned, 2-way banks)
#define VROW 52       // fp16 row stride for vT (rows are V *columns*)
#define OROW 260      // fp32 row stride for out staging

__device__ __forceinline__ uint cvt2_u32(float a, float b) {
    auto t = __builtin_amdgcn_cvt_pkrtz(a, b);
    return *(uint*)&t;
}
__device__ __forceinline__ f16x4 mk4(uint a, uint b) {
    union { uint u[2]; f16x4 v; } x;
    x.u[0] = a; x.u[1] = b;
    return x.v;
}

// --- Kernel A: pos MLP table, (169, 8) fp32 ---
__global__ void pos_mlp_kernel(const float* __restrict__ W1, const float* __restrict__ b1,
                               const float* __restrict__ W2, const float* __restrict__ b2,
                               float* __restrict__ pos) {
    int idx = blockIdx.x * blockDim.x + threadIdx.x;
    if (idx >= 169) return;
    float bh = (float)(idx / 13) - 6.0f;
    float bw = (float)(idx % 13) - 6.0f;
    float outv[NH];
#pragma unroll
    for (int t = 0; t < NH; ++t) outv[t] = b2[t];
    for (int u = 0; u < 64; ++u) {
        float hv = fmaf(bh, W1[u], fmaf(bw, W1[64 + u], b1[u]));
        hv = fmaxf(hv, 0.0f);
#pragma unroll
        for (int t = 0; t < NH; ++t) outv[t] = fmaf(hv, W2[u * NH + t], outv[t]);
    }
#pragma unroll
    for (int t = 0; t < NH; ++t) pos[idx * NH + t] = outv[t];
}

// --- Kernel B: bias (×log2e) in S^T MFMA C/D fragment layout, -1e30 mask for j>=49 ---
__global__ void bias_frag_kernel(const float* __restrict__ pos, float* __restrict__ bfrag) {
    int blk = blockIdx.x;           // ((h*4 + jt)*4 + it), 128 blocks
    int it = blk & 3, jt = (blk >> 2) & 3, h = blk >> 4;
    int lane = threadIdx.x;
    int g = lane >> 4, l15 = lane & 15;
    int i = it * 16 + l15;
    float4 v;
    float* vp = (float*)&v;
#pragma unroll
    for (int r = 0; r < 4; ++r) {
        int j = jt * 16 + g * 4 + r;
        float val;
        if (j >= NWIN) val = -1e30f;                       // exp2 -> 0 (kills clamped K rows)
        else if (i >= NWIN) val = 0.0f;
        else {
            int rel = (i / 7 - j / 7 + 6) * 13 + (i % 7 - j % 7 + 6);
            val = pos[rel * NH + h] * 1.4426950408889634f; // fold log2e
        }
        vp[r] = val;
    }
    *(float4*)(bfrag + (size_t)blk * 256 + lane * 4) = v;
}

// --- Kernel C: 512 threads = 8 waves = 8 heads of ONE window.
//     ALL HBM traffic contiguous-streamed (1KB per wave-instruction).
//     LDS fragment reads CLAMPED to row 48 (pad rows never read -> no NaN).
__global__ __launch_bounds__(512, 4) void attn_kernel(
    const float* __restrict__ q, const float* __restrict__ k,
    const float* __restrict__ v, const float* __restrict__ bfrag,
    float* __restrict__ out) {
    // pool: qh[49*264] kh[49*264] vT[256*52] fp16 = 78368 B; out staging (fp32
    // [64][260] = 66560 B) overlays the pool after all LDS reads complete.
    __shared__ __align__(16) ushort pool[39184];
    ushort* qh = pool;                  // rows 0..48 written
    ushort* kh = pool + 12936;
    ushort* vT = pool + 25872;          // [256][52], rows 0..48 written
    float* ldsOut = (float*)pool;

    // Bijective XCD swizzle (gridDim.x = 2048, divisible by 8)
    const int nper = (int)(gridDim.x >> 3);
    const int b = ((int)blockIdx.x & 7) * nper + ((int)blockIdx.x >> 3);

    const int tid = threadIdx.x;
    const int w = tid >> 6, lane = tid & 63;   // w = head
    const int h = w;
    const int g = lane >> 4, l15 = lane & 15;
    const size_t wbase = (size_t)b * (NWIN * CCH);

    // ======== Phase 0: streaming stage q,k,v (contiguous float4 per lane) ========
#pragma unroll
    for (int it = 0; it < 7; ++it) {
        int s = it * 512 + tid;
        if (s < NF4) {
            int row = s >> 6;              // 64 float4 per 1KB row -> rows 0..48
            int col = (s & 63) * 4;
            float4 q4 = *(const float4*)(q + wbase + (size_t)s * 4);
            float4 k4 = *(const float4*)(k + wbase + (size_t)s * 4);
            float4 v4 = *(const float4*)(v + wbase + (size_t)s * 4);
            uint2 qw; qw.x = cvt2_u32(q4.x, q4.y); qw.y = cvt2_u32(q4.z, q4.w);
            uint2 kw; kw.x = cvt2_u32(k4.x, k4.y); kw.y = cvt2_u32(k4.z, k4.w);
            uint v01 = cvt2_u32(v4.x, v4.y), v23 = cvt2_u32(v4.z, v4.w);
            *(uint2*)&qh[row * QROW + col] = qw;
            *(uint2*)&kh[row * QROW + col] = kw;
            vT[(col + 0) * VROW + row] = (ushort)(v01 & 0xffffu);
            vT[(col + 1) * VROW + row] = (ushort)(v01 >> 16);
            vT[(col + 2) * VROW + row] = (ushort)(v23 & 0xffffu);
            vT[(col + 3) * VROW + row] = (ushort)(v23 >> 16);
        }
    }
    __syncthreads();

    // ======== Phase 1: fragment reads from LDS, row-clamped to 48 ========
    f16x8 ka16[4], qb16[4];
#pragma unroll
    for (int t = 0; t < 4; ++t) {
        int row = t * 16 + l15;
        int rc = row < NWIN ? row : NWIN - 1;   // pad rows read real row 48 (finite)
        ka16[t] = *(const f16x8*)&kh[rc * QROW + h * 32 + g * 8];   // killed by -1e30 bias
        qb16[t] = *(const f16x8*)&qh[rc * QROW + h * 32 + g * 8];   // never stored
    }
    f16x4 vf[4][2];   // [jt][nt]: V[jt*16+4g+r][h*32+nt*16+l15]
#pragma unroll
    for (int jt = 0; jt < 3; ++jt)
#pragma unroll
        for (int nt = 0; nt < 2; ++nt)
            vf[jt][nt] = *(const f16x4*)&vT[(h * 32 + nt * 16 + l15) * VROW + jt * 16 + 4 * g];
#pragma unroll
    for (int nt = 0; nt < 2; ++nt) {   // jt=3: element-wise, clamped (j>=49 -> row 48; P=0 kills)
        int colbase = (h * 32 + nt * 16 + l15) * VROW;
        union { ushort u[4]; f16x4 v; } x;
#pragma unroll
        for (int r = 0; r < 4; ++r) {
            int j = 48 + 4 * g + r;
            int jc = j < NWIN ? j : NWIN - 1;
            x.u[r] = vT[colbase + jc];
        }
        vf[3][nt] = x.v;
    }
    __syncthreads();   // all LDS reads done; pool reusable for output staging

    // ======== Phase 2: QK^T (swapped): acc[jt][it] = S^T tile ========
    f32x4 acc[4][4];
#pragma unroll
    for (int jt = 0; jt < 4; ++jt)
#pragma unroll
        for (int it = 0; it < 4; ++it) {
            f32x4 a = {0.f, 0.f, 0.f, 0.f};
            acc[jt][it] = __builtin_amdgcn_mfma_f32_16x16x32_f16(ka16[jt], qb16[it], a, 0, 0, 0);
        }

    // ======== Phase 3: softmax per column i; P stays in registers (16x16x16 A-frags) ========
    const float scale2 = 0.17677669529663687f * 1.4426950408889634f;
    f16x4 pf[4][4];   // [jt][it]
#pragma unroll
    for (int it = 0; it < 4; ++it) {
        float p[16];
        float s = 0.0f;
#pragma unroll
        for (int jt = 0; jt < 4; ++jt) {
            f32x4 bb = *(const f32x4*)(bfrag + (size_t)((h * 4 + jt) * 4 + it) * 256 + lane * 4);
#pragma unroll
            for (int r = 0; r < 4; ++r) {
                float e = __builtin_amdgcn_exp2f(fmaf(acc[jt][it][r], scale2, bb[r]));
                p[jt * 4 + r] = e;
                s += e;
            }
        }
        s += __shfl_xor(s, 16);
        s += __shfl_xor(s, 32);
        const float inv = 1.0f / s;
#pragma unroll
        for (int jt = 0; jt < 4; ++jt)
            pf[jt][it] = mk4(cvt2_u32(p[jt * 4 + 0] * inv, p[jt * 4 + 1] * inv),
                             cvt2_u32(p[jt * 4 + 2] * inv, p[jt * 4 + 3] * inv));
    }

    // ======== Phase 4: PV — 32x mfma_f32_16x16x16_f16 ========
    f32x4 oacc[4][2];
#pragma unroll
    for (int mt = 0; mt < 4; ++mt)
#pragma unroll
        for (int nt = 0; nt < 2; ++nt) oacc[mt][nt] = (f32x4){0.f, 0.f, 0.f, 0.f};
#pragma unroll
    for (int jt = 0; jt < 4; ++jt)
#pragma unroll
        for (int mt = 0; mt < 4; ++mt)
#pragma unroll
            for (int nt = 0; nt < 2; ++nt)
                oacc[mt][nt] = __builtin_amdgcn_mfma_f32_16x16x16f16(pf[jt][mt], vf[jt][nt],
                                                                     oacc[mt][nt], 0, 0, 0);

    // ======== Phase 5: stage O in LDS (rows i>=49 land in dead pool space) ========
#pragma unroll
    for (int mt = 0; mt < 4; ++mt)
#pragma unroll
        for (int r = 0; r < 4; ++r) {
            int i = mt * 16 + g * 4 + r;
            ldsOut[i * OROW + h * 32 + l15]      = oacc[mt][0][r];
            ldsOut[i * OROW + h * 32 + 16 + l15] = oacc[mt][1][r];
        }
    __syncthreads();

    // ======== Phase 6: streaming store (contiguous 1KB per wave-instruction) ========
#pragma unroll
    for (int it = 0; it < 7; ++it) {
        int s = it * 512 + tid;
        if (s < NF4) {
            int row = s >> 6;
            int col = (s & 63) * 4;
            *(float4*)(out + wbase + (size_t)s * 4) = *(const float4*)&ldsOut[row * OROW + col];
        }
    }
}

extern "C" void kernel_launch(void* const* d_in, const int* in_sizes, int n_in,
                              void* d_out, int out_size, void* d_ws, size_t ws_size,
                              hipStream_t stream) {
    const float* q  = (const float*)d_in[0];
    const float* k  = (const float*)d_in[1];
    const float* v  = (const float*)d_in[2];
    const float* W1 = (const float*)d_in[3];
    const float* b1 = (const float*)d_in[4];
    const float* W2 = (const float*)d_in[5];
    const float* b2 = (const float*)d_in[6];

    float* pos   = (float*)d_ws;                       // 169*8 fp32
    float* bfrag = (float*)((char*)d_ws + 8192);       // 128*256 fp32 = 131072 B
    float* out   = (float*)d_out;

    const int B = in_sizes[0] / (NWIN * CCH);          // 2048 (divisible by 8)

    pos_mlp_kernel<<<1, 192, 0, stream>>>(W1, b1, W2, b2, pos);
    bias_frag_kernel<<<128, 64, 0, stream>>>(pos, bfrag);
    attn_kernel<<<B, 512, 0, stream>>>(q, k, v, bfrag, out);
}